// Round 13
// baseline (1433.386 us; speedup 1.0000x reference)
//
#include <hip/hip_runtime.h>

// ---------------------------------------------------------------------------
// FUSED kernel: GEMM producer + sequential LIF scan consumer in ONE dispatch.
//   blockIdx 0..B-1        : scan blocks (one per sample; R11 body verbatim)
//   blockIdx B..B+2*T-1    : GEMM tile blocks (i_x[t] = x_t@w_in), mb==t
// Sync: flags[t>>2] counts release-scoped wave-adds (8 waves per t: 2 tile
// blocks x 4 waves); a chunk of 4 timesteps is ready at 32. Scan spins with
// acquire loads (+s_sleep) — agent-scope acq/rel handles cross-XCD L2
// non-coherence. Scan waves run at s_setprio(3) so concurrent GEMM waves
// don't steal their issue slots. No deadlock: 128 scan blocks cannot fill
// the 2048 block slots, so GEMM blocks always get CUs and complete.
// i_x staging aliases the zs output region: row t is written by GEMM,
// flag-released, read by scan, then overwritten by scan's z output.
// ---------------------------------------------------------------------------
__global__ __launch_bounds__(256) void lif_fused(const float* __restrict__ X,
                                                 const float* __restrict__ W,
                                                 const float* __restrict__ wrec,
                                                 const float* __restrict__ z0,
                                                 const float* __restrict__ v0,
                                                 const float* __restrict__ t0,
                                                 float* __restrict__ zs,
                                                 float* __restrict__ vs,
                                                 int* __restrict__ flags,
                                                 int T, int B) {
    __shared__ float As[32][132];
    __shared__ float Bs[32][128];
    __shared__ unsigned long long smask[2][4];

    const int tid = threadIdx.x;

    if ((int)blockIdx.x >= B) {
        // ===================== GEMM producer path =====================
        const int gb = blockIdx.x - B;
        const int mb = gb >> 1;          // == timestep t (B == 128)
        const int nb = gb & 1;
        const int m0 = mb << 7;
        const int n0 = nb << 7;
        const int tr = (tid >> 4) << 3;
        const int tc = (tid & 15) << 3;

        float acc[8][8];
#pragma unroll
        for (int i = 0; i < 8; ++i)
#pragma unroll
            for (int j = 0; j < 8; ++j) acc[i][j] = 0.f;

        for (int kb = 0; kb < 256; kb += 32) {
#pragma unroll
            for (int i = 0; i < 4; ++i) {
                int f = tid + (i << 8);
                int row = f >> 3, kq = f & 7;
                float4 a = *(const float4*)(X + (size_t)(m0 + row) * 256 + kb + (kq << 2));
                As[(kq << 2) + 0][row] = a.x;
                As[(kq << 2) + 1][row] = a.y;
                As[(kq << 2) + 2][row] = a.z;
                As[(kq << 2) + 3][row] = a.w;
                int rowb = f >> 5, cq = f & 31;
                *(float4*)&Bs[rowb][cq << 2] =
                    *(const float4*)(W + (size_t)(kb + rowb) * 256 + n0 + (cq << 2));
            }
            __syncthreads();
#pragma unroll
            for (int k = 0; k < 32; ++k) {
                float a[8], bb[8];
                *(float4*)&a[0] = *(const float4*)&As[k][tr];
                *(float4*)&a[4] = *(const float4*)&As[k][tr + 4];
                *(float4*)&bb[0] = *(const float4*)&Bs[k][tc];
                *(float4*)&bb[4] = *(const float4*)&Bs[k][tc + 4];
#pragma unroll
                for (int i = 0; i < 8; ++i)
#pragma unroll
                    for (int j = 0; j < 8; ++j)
                        acc[i][j] = fmaf(a[i], bb[j], acc[i][j]);
            }
            __syncthreads();
        }
#pragma unroll
        for (int i = 0; i < 8; ++i) {
            float* yp = zs + (size_t)(m0 + tr + i) * 256 + n0 + tc;
            *(float4*)yp = make_float4(acc[i][0], acc[i][1], acc[i][2], acc[i][3]);
            *(float4*)(yp + 4) = make_float4(acc[i][4], acc[i][5], acc[i][6], acc[i][7]);
        }
        // release: one add per WAVE (release fence drains THIS wave's stores)
        if ((tid & 63) == 0)
            __hip_atomic_fetch_add(&flags[mb >> 2], 1, __ATOMIC_RELEASE,
                                   __HIP_MEMORY_SCOPE_AGENT);
        return;
    }

    // ===================== scan consumer path (R11 body) =====================
    __builtin_amdgcn_s_setprio(3);

    const int b = blockIdx.x;
    const int wv = tid >> 6;
    const int lane = tid & 63;
    const size_t sb = (size_t)b * 256 + tid;
    const size_t stride = (size_t)B * 256;

    float v = v0[sb];
    float t = t0[sb];
    bool sp = (z0[sb] != 0.f);
    int p = 0;

    const float* ixp = zs + sb;          // i_x staged in zs region

    constexpr float G0 = 1e-5f + 1.0f;   // g(0), exact

    auto waitChunk = [&](int c0) {
        int k = ((c0 < T) ? c0 : (T - 1)) >> 2;
        int hi = 4 * (k + 1); if (hi > T) hi = T;
        int need = 8 * (hi - 4 * k);     // 8 wave-adds per ready timestep
        while (__hip_atomic_load(&flags[k], __ATOMIC_ACQUIRE,
                                 __HIP_MEMORY_SCOPE_AGENT) < need)
            __builtin_amdgcn_s_sleep(32);
    };

    auto step = [&](float rr, float& zo_, float& vo_) {
        unsigned long long mk = __ballot(sp);
        if (lane == 0) smask[p][wv] = mk;
        __syncthreads();
        unsigned long long m0 = smask[p][0];
        unsigned long long m1 = smask[p][1];
        unsigned long long m2 = smask[p][2];
        unsigned long long m3 = smask[p][3];
        p ^= 1;

        // speculative leak math in the LDS-read shadow (ir==0 => i_in==rr)
        float vc = fmaxf(sp ? 0.f : v, -1.f);
        float E  = __builtin_amdgcn_exp2f(fabsf(vc));
        float cA = (1e-5f + (E - 1.f)) + 1.f;
        float tp1 = t + 1.f;
        bool hz = (rr == 0.f);
        float cT = hz ? G0 : ((1e-5f + tp1) + 1.f);
        float L  = __builtin_amdgcn_logf(fminf(cT, cA));
        float Ls = copysignf(L, vc);
        float nvp = (vc == 0.f) ? vc : (vc - Ls);
        float nv  = nvp + rr;
        float ntn = hz ? tp1 : 0.f;

        if ((m0 | m1 | m2 | m3) != 0ull) {
            float ir = 0.f;
            unsigned long long mm;
            mm = m0;
            while (mm) { int j = __builtin_ctzll(mm); mm &= mm - 1;
                ir += wrec[((size_t)j << 8) + tid]; }
            mm = m1;
            while (mm) { int j = __builtin_ctzll(mm); mm &= mm - 1;
                ir += wrec[((size_t)(64 + j) << 8) + tid]; }
            mm = m2;
            while (mm) { int j = __builtin_ctzll(mm); mm &= mm - 1;
                ir += wrec[((size_t)(128 + j) << 8) + tid]; }
            mm = m3;
            while (mm) { int j = __builtin_ctzll(mm); mm &= mm - 1;
                ir += wrec[((size_t)(192 + j) << 8) + tid]; }

            float i_in = rr + ir;
            bool hz2 = (i_in == 0.f);
            float cT2 = hz2 ? G0 : ((1e-5f + tp1) + 1.f);
            float L2  = __builtin_amdgcn_logf(fminf(cT2, cA));
            float Ls2 = copysignf(L2, vc);
            float nvp2 = (vc == 0.f) ? vc : (vc - Ls2);
            nv  = nvp2 + i_in;
            ntn = hz2 ? tp1 : 0.f;
        }

        sp = (nv > 0.5f);
        v = nv;
        t = ntn;
        zo_ = sp ? 1.f : 0.f;
        vo_ = nv;
    };

    float iA[4], iB[4], zo[4], vo[4];

    auto loadChunk = [&](float (&bf)[4], int c0) {
#pragma unroll
        for (int u = 0; u < 4; ++u) {
            int r = c0 + u;
            r = (r < T) ? r : T - 1;
            bf[u] = ixp[(size_t)r * stride];
        }
    };

    auto runChunk = [&](float (&bf)[4], int c0) {
#pragma unroll
        for (int u = 0; u < 4; ++u) step(bf[u], zo[u], vo[u]);
#pragma unroll
        for (int u = 0; u < 4; ++u) {
            size_t o = (size_t)(c0 + u) * stride + sb;
            zs[o] = zo[u];
            vs[o] = vo[u];
        }
    };

    waitChunk(0);
    loadChunk(iA, 0);
    int c = 0;
    while (c + 8 <= T) {
        waitChunk(c + 4);
        loadChunk(iB, c + 4);
        runChunk(iA, c);
        waitChunk(c + 8);                 // dummy-load wait clamps to last flag
        loadChunk(iA, c + 8);
        runChunk(iB, c + 4);
        c += 8;
    }
    if (c + 4 <= T) {
        runChunk(iA, c);
        c += 4;
    }
    for (int ts = c; ts < T; ++ts) {
        waitChunk(ts);
        float r = ixp[(size_t)ts * stride];
        float zz, vv;
        step(r, zz, vv);
        size_t o = (size_t)ts * stride + sb;
        zs[o] = zz;
        vs[o] = vv;
    }
}

extern "C" void kernel_launch(void* const* d_in, const int* in_sizes, int n_in,
                              void* d_out, int out_size, void* d_ws, size_t ws_size,
                              hipStream_t stream) {
    const float* x    = (const float*)d_in[0];
    const float* z0   = (const float*)d_in[1];
    const float* v0   = (const float*)d_in[2];
    const float* t0   = (const float*)d_in[3];
    const float* w_in = (const float*)d_in[4];
    const float* wrec = (const float*)d_in[5];

    const int n_rec = 256;
    const int B = in_sizes[1] / n_rec;          // 128
    const int nin = in_sizes[4] / n_rec;        // 256
    const int T = in_sizes[0] / (B * nin);      // 1000
    const int M = T * B;                        // 128000

    float* zs = (float*)d_out;
    float* vs = zs + (size_t)T * B * n_rec;
    int* flags = (int*)d_ws;
    const int nflags = (T + 3) / 4;

    // zero the producer-consumer flags every launch (deterministic; d_ws is
    // not re-poisoned between replays)
    hipMemsetAsync(flags, 0, (size_t)nflags * sizeof(int), stream);

    const int gemmBlocks = (M / 128) * 2;       // 2000, mb == t since B==128
    lif_fused<<<dim3(B + gemmBlocks), dim3(256), 0, stream>>>(
        x, w_in, wrec, z0, v0, t0, zs, vs, flags, T, B);
}